// Round 11
// baseline (107.346 us; speedup 1.0000x reference)
//
#include <hip/hip_runtime.h>
#include <stdint.h>

#define T_ROWS 256
#define KF 4096
#define OF 11008
// grouped (dest) segment layout: [0,3712) 4-bit, [3712,3968) 6-bit, [3968,4096) 8-bit

typedef int   v4i __attribute__((ext_vector_type(4)));
typedef float v4f __attribute__((ext_vector_type(4)));

typedef const __attribute__((address_space(1))) uint8_t* gptr_t;
typedef __attribute__((address_space(3))) uint8_t* lptr_t;

// ---------------------------------------------------------------------------
// Kernel 0 (R8-verified): stable partition of source columns by segment.
// ---------------------------------------------------------------------------
__global__ __launch_bounds__(256) void perm_k(const int* __restrict__ idx,
                                              int* __restrict__ src_of) {
    __shared__ uint8_t g[KF];
    __shared__ int cnt[3][256];
    __shared__ int exc[3][256];
    const int t = threadIdx.x;
    for (int i = 0; i < 16; ++i) {
        int p = t * 16 + i;
        int seg = p < 3712 ? 0 : (p < 3968 ? 1 : 2);
        g[idx[p]] = (uint8_t)seg;
    }
    __syncthreads();
    int c0 = 0, c1 = 0, c2 = 0;
    for (int i = 0; i < 16; ++i) {
        int s = g[t * 16 + i];
        c0 += (s == 0); c1 += (s == 1); c2 += (s == 2);
    }
    cnt[0][t] = c0; cnt[1][t] = c1; cnt[2][t] = c2;
    __syncthreads();
    if (t < 192) {                       // wave s scans segment s
        int s = t >> 6, l = t & 63;
        int run = 0;
        for (int j = 0; j < 4; ++j) {
            int x = cnt[s][j * 64 + l];
            int inc = x;
#pragma unroll
            for (int off = 1; off < 64; off <<= 1) {
                int y = __shfl_up(inc, off);
                if (l >= off) inc += y;
            }
            exc[s][j * 64 + l] = run + inc - x;
            run += __shfl(inc, 63);
        }
    }
    __syncthreads();
    int off0 = exc[0][t], off1 = 3712 + exc[1][t], off2 = 3968 + exc[2][t];
    for (int i = 0; i < 16; ++i) {
        int c = t * 16 + i;
        int s = g[c];
        int d = (s == 0) ? off0++ : (s == 1) ? off1++ : off2++;
        src_of[d] = c;
    }
}

// ---------------------------------------------------------------------------
// Kernel 1: R8 quant, DIAGNOSTIC build. W-blocks run the full per-row body
// 3x (idempotent identical passes; passes 2-3 re-stage an L2-hot row).
// Delta vs R8's 79.1 us = 2x quant_W machinery time (LDS+barrier+gather+VALU,
// HBM excluded). Output state identical to R8.
// ---------------------------------------------------------------------------
__global__ __launch_bounds__(256) void quant_k(const float* __restrict__ x,
                                               const float* __restrict__ W,
                                               const int* __restrict__ src_of,
                                               int8_t* __restrict__ qX,
                                               int8_t* __restrict__ qW,
                                               float* __restrict__ sX,
                                               float* __restrict__ sW) {
    __shared__ float rowbuf[KF];
    __shared__ float lmax[256];
    __shared__ float sm[3];
    const int b = blockIdx.x;
    const int t = threadIdx.x;
    const int w = t >> 6, ln = t & 63;
    const float* src; int8_t* qout; float* scales; int r; int nrows;
    bool isX;
    if (b < T_ROWS) { src = x; qout = qX; scales = sX; r = b; nrows = T_ROWS; isX = true; }
    else           { src = W; qout = qW; scales = sW; r = b - T_ROWS; nrows = OF; isX = false; }
    const float* row = src + (size_t)r * KF;

    const int seg = t < 232 ? 0 : (t < 248 ? 1 : 2);
    const float qmax = seg == 0 ? 7.f : (seg == 1 ? 31.f : 127.f);
    int c[16];
#pragma unroll
    for (int i = 0; i < 4; ++i) {
        v4i ci = *(const v4i*)&src_of[t * 16 + i * 4];
        c[i*4+0] = ci[0]; c[i*4+1] = ci[1]; c[i*4+2] = ci[2]; c[i*4+3] = ci[3];
    }

    const int npass = isX ? 1 : 3;       // DIAGNOSTIC: triple machinery on W
    for (int pass = 0; pass < npass; ++pass) {
        // async stage 16 KB: 4 x 16B per thread, wave-uniform LDS base + lane*16
#pragma unroll
        for (int j = 0; j < 4; ++j) {
            const uint8_t* srcp = (const uint8_t*)(row + j * 1024 + t * 4);
            __builtin_amdgcn_global_load_lds((gptr_t)srcp, (lptr_t)&rowbuf[j * 1024 + w * 256], 16, 0, 0);
        }
        asm volatile("s_waitcnt vmcnt(0)" ::: "memory");
        __syncthreads();

        float v[16];
        float mx = 0.f;
#pragma unroll
        for (int i = 0; i < 16; ++i) { v[i] = rowbuf[c[i]]; mx = fmaxf(mx, fabsf(v[i])); }
        lmax[t] = mx;
        __syncthreads();
        if (w == 0) {
            float m = fmaxf(fmaxf(lmax[ln], lmax[ln + 64]), lmax[ln + 128]);
            if (ln < 40) m = fmaxf(m, lmax[ln + 192]);
#pragma unroll
            for (int off = 32; off; off >>= 1) m = fmaxf(m, __shfl_xor(m, off));
            if (ln == 0) sm[0] = m;
        } else if (w == 1) {
            float m = ln < 16 ? lmax[232 + ln] : 0.f;
#pragma unroll
            for (int off = 8; off; off >>= 1) m = fmaxf(m, __shfl_xor(m, off));
            if (ln == 0) sm[1] = m;
        } else if (w == 2) {
            float m = ln < 8 ? lmax[248 + ln] : 0.f;
#pragma unroll
            for (int off = 4; off; off >>= 1) m = fmaxf(m, __shfl_xor(m, off));
            if (ln == 0) sm[2] = m;
        }
        __syncthreads();
        float s = sm[seg] / qmax;
        if (s == 0.f) s = 1.f;
        if (t == 0 || t == 232 || t == 248) scales[seg * nrows + r] = s;
        const float rs = 1.0f / s;
        union { int8_t bb[16]; v4i q; } u;
#pragma unroll
        for (int i = 0; i < 16; ++i) {
            float qv = rintf(fminf(fmaxf(v[i] * rs, -qmax), qmax));  // RNE == np.round
            u.bb[i] = (int8_t)qv;
        }
        *(v4i*)(qout + (size_t)r * KF + t * 16) = u.q;
        __syncthreads();                 // rowbuf safe to overwrite next pass
        asm volatile("" ::: "memory");
    }
}

// ---------------------------------------------------------------------------
// Kernel 2 (R5-verified, unchanged): int8 MFMA GEMM, 128x64 tile, grid 344,
// 4 waves. BK=128, 32 steps.
// A (qX, 1 MB, L2-resident): per-lane global->reg dwordx4, double-buffered.
// B (qW): global_load_lds 3-slot ring, ^(row&7) 16B-chunk swizzle.
// One wait per step: s_waitcnt vmcnt(6) lgkmcnt(0) + sched_barrier(0).
// Segment flushes after steps 28/30 (K = 3712 / 3968).
// ---------------------------------------------------------------------------
__global__ __launch_bounds__(256, 2)
void gemm_k(const int8_t* __restrict__ qX, const int8_t* __restrict__ qW,
            const float* __restrict__ sX, const float* __restrict__ sW,
            const float* __restrict__ bias, float* __restrict__ out) {
    __shared__ __align__(16) int8_t lB[3][64 * 128];

    const int bid = blockIdx.x;
    const int swz = (bid & 7) * 43 + (bid >> 3);  // 344 = 8*43: bijective
    const int row0 = (swz & 1) * 128;
    const int col0 = (swz >> 1) * 64;
    const int tid = threadIdx.x;
    const int lane = tid & 63;
    const int w = tid >> 6;
    const int lr = lane >> 3, lc = lane & 7;
    const int kg = lane >> 4;     // 0..3: K-chunk group
    const int cr = lane & 15;     // row/col within fragment

    v4i iacc[2][4];
    v4f facc[2][4];
#pragma unroll
    for (int m = 0; m < 2; ++m)
#pragma unroll
        for (int n = 0; n < 4; ++n) {
            iacc[m][n][0]=0; iacc[m][n][1]=0; iacc[m][n][2]=0; iacc[m][n][3]=0;
            facc[m][n][0]=0.f; facc[m][n][1]=0.f; facc[m][n][2]=0.f; facc[m][n][3]=0.f;
        }

    const int8_t* aRow[2];
    aRow[0] = qX + (size_t)(row0 + w * 32 + cr) * KF;
    aRow[1] = qX + (size_t)(row0 + w * 32 + 16 + cr) * KF;

    auto stageB = [&](int slot, int step) {
        const int k0 = step * 128;
        const int sc = (lc ^ lr) << 4;            // pre-swizzled source chunk
#pragma unroll
        for (int j = 0; j < 2; ++j) {
            const int brow = j * 32 + w * 8;      // +lr comes from lane offset
            const uint8_t* src = (const uint8_t*)qW + (size_t)(col0 + brow + lr) * KF + k0 + sc;
            __builtin_amdgcn_global_load_lds((gptr_t)src, (lptr_t)&lB[slot][brow * 128], 16, 0, 0);
        }
    };

    auto loadA = [&](v4i (&a)[2][2], int step) {
        const int kb = step * 128 + kg * 16;
#pragma unroll
        for (int m = 0; m < 2; ++m)
#pragma unroll
            for (int kk = 0; kk < 2; ++kk) {
                const int8_t* p = aRow[m] + kb + kk * 64;
                asm volatile("global_load_dwordx4 %0, %1, off"
                             : "=v"(a[m][kk]) : "v"(p) : "memory");
            }
    };

    auto flush = [&](int seg) {
#pragma unroll
        for (int m = 0; m < 2; ++m) {
            float sa[4];
#pragma unroll
            for (int rr = 0; rr < 4; ++rr)
                sa[rr] = sX[seg * T_ROWS + row0 + w * 32 + m * 16 + ((lane >> 4) << 2) + rr];
#pragma unroll
            for (int n = 0; n < 4; ++n) {
                const float sb = sW[seg * OF + col0 + n * 16 + (lane & 15)];
#pragma unroll
                for (int rr = 0; rr < 4; ++rr) {
                    facc[m][n][rr] += (float)iacc[m][n][rr] * (sa[rr] * sb);
                    iacc[m][n][rr] = 0;
                }
            }
        }
    };

    auto body = [&](int t, v4i (&aCur)[2][2], v4i (&aNext)[2][2]) {
        __builtin_amdgcn_s_barrier();
        // B fragments from LDS (lgkm-tracked)
        v4i bf[4][2];
        const int8_t* pb = &lB[t % 3][0];
#pragma unroll
        for (int n = 0; n < 4; ++n) {
            const int brow = n * 16 + cr;
#pragma unroll
            for (int kk = 0; kk < 2; ++kk) {
                const int ch = (kk * 4 + kg) ^ (brow & 7);
                bf[n][kk] = *(const v4i*)(pb + brow * 128 + ch * 16);
            }
        }
        // issue next prefetches (stay in flight across the wait)
        if (t + 2 < 32) stageB((t + 2) % 3, t + 2);
        if (t + 1 < 32) loadA(aNext, t + 1);
        // single wait point: aCur + B(t+1) retired; 6 newest stay in flight
        if (t < 30)       asm volatile("s_waitcnt vmcnt(6) lgkmcnt(0)" ::: "memory");
        else if (t == 30) asm volatile("s_waitcnt vmcnt(4) lgkmcnt(0)" ::: "memory");
        else              asm volatile("s_waitcnt vmcnt(0) lgkmcnt(0)" ::: "memory");
        __builtin_amdgcn_sched_barrier(0);
#pragma unroll
        for (int kk = 0; kk < 2; ++kk)
#pragma unroll
            for (int m = 0; m < 2; ++m)
#pragma unroll
                for (int n = 0; n < 4; ++n)
                    iacc[m][n] = __builtin_amdgcn_mfma_i32_16x16x64_i8(aCur[m][kk], bf[n][kk], iacc[m][n], 0, 0, 0);
        if (t == 28) flush(0);          // seg0: K [0,3712)
        else if (t == 30) flush(1);     // seg1: K [3712,3968)
    };

    v4i aA[2][2], aB[2][2];
    stageB(0, 0);
    stageB(1, 1);
    loadA(aA, 0);
    asm volatile("s_waitcnt vmcnt(6)" ::: "memory");   // B(0) landed

    for (int tt = 0; tt < 32; tt += 2) {
        body(tt,     aA, aB);
        body(tt + 1, aB, aA);
    }
    flush(2);                           // seg2: K [3968,4096)

#pragma unroll
    for (int m = 0; m < 2; ++m)
#pragma unroll
        for (int n = 0; n < 4; ++n) {
            const int colg = col0 + n * 16 + (lane & 15);
            const float bv = bias[colg];
#pragma unroll
            for (int rr = 0; rr < 4; ++rr) {
                const int rowg = row0 + w * 32 + m * 16 + ((lane >> 4) << 2) + rr;
                out[(size_t)rowg * OF + colg] = facc[m][n][rr] + bv;
            }
        }
}

// ---------------------------------------------------------------------------
// workspace layout (bytes):
//   qX     @ 0          :  1,048,576
//   qW     @ 1,048,576  : 45,088,768
//   sX     @ 46,137,344 :      3,072
//   sW     @ 46,140,416 :    132,096
//   src_of @ 46,272,512 :     16,384
// ---------------------------------------------------------------------------
extern "C" void kernel_launch(void* const* d_in, const int* in_sizes, int n_in,
                              void* d_out, int out_size, void* d_ws, size_t ws_size,
                              hipStream_t stream) {
    const float* x    = (const float*)d_in[0];
    const float* W    = (const float*)d_in[1];
    const float* bias = (const float*)d_in[2];
    const int*   ridx = (const int*)d_in[3];
    float* out = (float*)d_out;

    uint8_t* ws = (uint8_t*)d_ws;
    int8_t* qX = (int8_t*)ws;
    int8_t* qW = (int8_t*)(ws + 1048576);
    float*  sX = (float*)(ws + 46137344);
    float*  sW = (float*)(ws + 46140416);
    int* src_of = (int*)(ws + 46272512);

    perm_k<<<1, 256, 0, stream>>>(ridx, src_of);
    quant_k<<<T_ROWS + OF, 256, 0, stream>>>(x, W, src_of, qX, qW, sX, sW);
    gemm_k<<<344, 256, 0, stream>>>(qX, qW, sX, sW, bias, out);
}

// Round 12
// 82.089 us; speedup vs baseline: 1.3077x; 1.3077x over previous
//
#include <hip/hip_runtime.h>
#include <stdint.h>

#define T_ROWS 256
#define KF 4096
#define OF 11008
// grouped (dest) segment layout: [0,3712) 4-bit, [3712,3968) 6-bit, [3968,4096) 8-bit

typedef int   v4i __attribute__((ext_vector_type(4)));
typedef float v4f __attribute__((ext_vector_type(4)));
typedef unsigned int u32;

typedef const __attribute__((address_space(1))) uint8_t* gptr_t;
typedef __attribute__((address_space(3))) uint8_t* lptr_t;

// ---------------------------------------------------------------------------
// Kernel 0: stable partition (R8-verified) + per-source-column segment tags.
// ---------------------------------------------------------------------------
__global__ __launch_bounds__(256) void perm_k(const int* __restrict__ idx,
                                              int* __restrict__ src_of,
                                              uint8_t* __restrict__ seg8) {
    __shared__ uint8_t g[KF];
    __shared__ int cnt[3][256];
    __shared__ int exc[3][256];
    const int t = threadIdx.x;
    for (int i = 0; i < 16; ++i) {
        int p = t * 16 + i;
        int seg = p < 3712 ? 0 : (p < 3968 ? 1 : 2);
        g[idx[p]] = (uint8_t)seg;
    }
    __syncthreads();
    int c0 = 0, c1 = 0, c2 = 0;
    for (int i = 0; i < 16; ++i) {
        int s = g[t * 16 + i];
        c0 += (s == 0); c1 += (s == 1); c2 += (s == 2);
    }
    cnt[0][t] = c0; cnt[1][t] = c1; cnt[2][t] = c2;
    __syncthreads();
    if (t < 192) {                       // wave s scans segment s
        int s = t >> 6, l = t & 63;
        int run = 0;
        for (int j = 0; j < 4; ++j) {
            int x = cnt[s][j * 64 + l];
            int inc = x;
#pragma unroll
            for (int off = 1; off < 64; off <<= 1) {
                int y = __shfl_up(inc, off);
                if (l >= off) inc += y;
            }
            exc[s][j * 64 + l] = run + inc - x;
            run += __shfl(inc, 63);
        }
    }
    __syncthreads();
    int off0 = exc[0][t], off1 = 3712 + exc[1][t], off2 = 3968 + exc[2][t];
    for (int i = 0; i < 16; ++i) {
        int c = t * 16 + i;
        int s = g[c];
        int d = (s == 0) ? off0++ : (s == 1) ? off1++ : off2++;
        src_of[d] = c;
        seg8[c] = (uint8_t)s;
    }
}

// ---------------------------------------------------------------------------
// Kernel 1: LEAN-MACHINERY quantize (R11 diagnostic: machinery was 14 us/pass).
// Row loaded coalesced to REGISTERS (no block-wide vmcnt(0) convoy); segment
// maxes computed in-register via seg8 tags (R9-verified masked-max) + shfl
// tree; registers ds_write_b128'd to rowbuf concurrently; ONE barrier; then
// the proven b32 gather + reciprocal quantize + b128 store.
// ---------------------------------------------------------------------------
__global__ __launch_bounds__(256) void quant_k(const float* __restrict__ x,
                                               const float* __restrict__ W,
                                               const int* __restrict__ src_of,
                                               const uint8_t* __restrict__ seg8,
                                               int8_t* __restrict__ qX,
                                               int8_t* __restrict__ qW,
                                               float* __restrict__ sX,
                                               float* __restrict__ sW) {
    __shared__ float rowbuf[KF];
    __shared__ float smw[3][4];
    const int b = blockIdx.x;
    const int t = threadIdx.x;
    const int w = t >> 6, ln = t & 63;
    const bool isX = b < T_ROWS;
    const int r = isX ? b : b - T_ROWS;
    const float* row = (isX ? x : W) + (size_t)r * KF;
    int8_t* qout = isX ? qX : qW;
    float* scales = isX ? sX : sW;
    const int nrows = isX ? T_ROWS : OF;

    const int seg = t < 232 ? 0 : (t < 248 ? 1 : 2);
    const float qmax = seg == 0 ? 7.f : (seg == 1 ? 31.f : 127.f);

    // gather map (dest-ordered) — independent loads, overlap everything below
    int c[16];
#pragma unroll
    for (int i = 0; i < 4; ++i) {
        v4i ci = *(const v4i*)&src_of[t * 16 + i * 4];
        c[i*4+0] = ci[0]; c[i*4+1] = ci[1]; c[i*4+2] = ci[2]; c[i*4+3] = ci[3];
    }

    // coalesced row load to registers + segment tags (source-ordered)
    v4f v[4]; u32 tg[4];
#pragma unroll
    for (int i = 0; i < 4; ++i) {
        v[i]  = *(const v4f*)(row + i * 1024 + t * 4);
        tg[i] = *(const u32*)(seg8 + i * 1024 + t * 4);
    }

    // in-register masked segment maxes (R9-verified pattern)
    float m0 = 0.f, m1 = 0.f, m2 = 0.f;
#pragma unroll
    for (int i = 0; i < 4; ++i)
#pragma unroll
        for (int j = 0; j < 4; ++j) {
            const int sj = (tg[i] >> (8 * j)) & 255;
            const float a = fabsf(v[i][j]);
            m0 = (sj == 0) ? fmaxf(m0, a) : m0;
            m1 = (sj == 1) ? fmaxf(m1, a) : m1;
            m2 = (sj == 2) ? fmaxf(m2, a) : m2;
        }
#pragma unroll
    for (int off = 32; off; off >>= 1) {
        m0 = fmaxf(m0, __shfl_xor(m0, off));
        m1 = fmaxf(m1, __shfl_xor(m1, off));
        m2 = fmaxf(m2, __shfl_xor(m2, off));
    }
    if (ln == 0) { smw[0][w] = m0; smw[1][w] = m1; smw[2][w] = m2; }

    // stage row to LDS for the gather (coalesced b128 writes)
#pragma unroll
    for (int i = 0; i < 4; ++i)
        *(v4f*)&rowbuf[i * 1024 + t * 4] = v[i];

    __syncthreads();    // the ONLY barrier

    const float mseg = fmaxf(fmaxf(smw[seg][0], smw[seg][1]),
                             fmaxf(smw[seg][2], smw[seg][3]));
    float s = mseg / qmax;
    if (s == 0.f) s = 1.f;
    if (t == 0) {
        float a0 = fmaxf(fmaxf(smw[0][0], smw[0][1]), fmaxf(smw[0][2], smw[0][3]));
        float a1 = fmaxf(fmaxf(smw[1][0], smw[1][1]), fmaxf(smw[1][2], smw[1][3]));
        float a2 = fmaxf(fmaxf(smw[2][0], smw[2][1]), fmaxf(smw[2][2], smw[2][3]));
        float s0 = a0 / 7.f;   if (s0 == 0.f) s0 = 1.f;
        float s1 = a1 / 31.f;  if (s1 == 0.f) s1 = 1.f;
        float s2 = a2 / 127.f; if (s2 == 0.f) s2 = 1.f;
        scales[r] = s0; scales[nrows + r] = s1; scales[2 * nrows + r] = s2;
    }
    const float rs = 1.0f / s;

    union { int8_t bb[16]; v4i q; } u;
#pragma unroll
    for (int i = 0; i < 16; ++i) {
        const float qv = rintf(fminf(fmaxf(rowbuf[c[i]] * rs, -qmax), qmax)); // RNE
        u.bb[i] = (int8_t)qv;
    }
    *(v4i*)(qout + (size_t)r * KF + t * 16) = u.q;
}

// ---------------------------------------------------------------------------
// Kernel 2 (R5-verified, unchanged): int8 MFMA GEMM, 128x64 tile, grid 344,
// 4 waves. BK=128, 32 steps.
// ---------------------------------------------------------------------------
__global__ __launch_bounds__(256, 2)
void gemm_k(const int8_t* __restrict__ qX, const int8_t* __restrict__ qW,
            const float* __restrict__ sX, const float* __restrict__ sW,
            const float* __restrict__ bias, float* __restrict__ out) {
    __shared__ __align__(16) int8_t lB[3][64 * 128];

    const int bid = blockIdx.x;
    const int swz = (bid & 7) * 43 + (bid >> 3);  // 344 = 8*43: bijective
    const int row0 = (swz & 1) * 128;
    const int col0 = (swz >> 1) * 64;
    const int tid = threadIdx.x;
    const int lane = tid & 63;
    const int w = tid >> 6;
    const int lr = lane >> 3, lc = lane & 7;
    const int kg = lane >> 4;     // 0..3: K-chunk group
    const int cr = lane & 15;     // row/col within fragment

    v4i iacc[2][4];
    v4f facc[2][4];
#pragma unroll
    for (int m = 0; m < 2; ++m)
#pragma unroll
        for (int n = 0; n < 4; ++n) {
            iacc[m][n][0]=0; iacc[m][n][1]=0; iacc[m][n][2]=0; iacc[m][n][3]=0;
            facc[m][n][0]=0.f; facc[m][n][1]=0.f; facc[m][n][2]=0.f; facc[m][n][3]=0.f;
        }

    const int8_t* aRow[2];
    aRow[0] = qX + (size_t)(row0 + w * 32 + cr) * KF;
    aRow[1] = qX + (size_t)(row0 + w * 32 + 16 + cr) * KF;

    auto stageB = [&](int slot, int step) {
        const int k0 = step * 128;
        const int sc = (lc ^ lr) << 4;            // pre-swizzled source chunk
#pragma unroll
        for (int j = 0; j < 2; ++j) {
            const int brow = j * 32 + w * 8;      // +lr comes from lane offset
            const uint8_t* src = (const uint8_t*)qW + (size_t)(col0 + brow + lr) * KF + k0 + sc;
            __builtin_amdgcn_global_load_lds((gptr_t)src, (lptr_t)&lB[slot][brow * 128], 16, 0, 0);
        }
    };

    auto loadA = [&](v4i (&a)[2][2], int step) {
        const int kb = step * 128 + kg * 16;
#pragma unroll
        for (int m = 0; m < 2; ++m)
#pragma unroll
            for (int kk = 0; kk < 2; ++kk) {
                const int8_t* p = aRow[m] + kb + kk * 64;
                asm volatile("global_load_dwordx4 %0, %1, off"
                             : "=v"(a[m][kk]) : "v"(p) : "memory");
            }
    };

    auto flush = [&](int seg) {
#pragma unroll
        for (int m = 0; m < 2; ++m) {
            float sa[4];
#pragma unroll
            for (int rr = 0; rr < 4; ++rr)
                sa[rr] = sX[seg * T_ROWS + row0 + w * 32 + m * 16 + ((lane >> 4) << 2) + rr];
#pragma unroll
            for (int n = 0; n < 4; ++n) {
                const float sb = sW[seg * OF + col0 + n * 16 + (lane & 15)];
#pragma unroll
                for (int rr = 0; rr < 4; ++rr) {
                    facc[m][n][rr] += (float)iacc[m][n][rr] * (sa[rr] * sb);
                    iacc[m][n][rr] = 0;
                }
            }
        }
    };

    auto body = [&](int t, v4i (&aCur)[2][2], v4i (&aNext)[2][2]) {
        __builtin_amdgcn_s_barrier();
        // B fragments from LDS (lgkm-tracked)
        v4i bf[4][2];
        const int8_t* pb = &lB[t % 3][0];
#pragma unroll
        for (int n = 0; n < 4; ++n) {
            const int brow = n * 16 + cr;
#pragma unroll
            for (int kk = 0; kk < 2; ++kk) {
                const int ch = (kk * 4 + kg) ^ (brow & 7);
                bf[n][kk] = *(const v4i*)(pb + brow * 128 + ch * 16);
            }
        }
        // issue next prefetches (stay in flight across the wait)
        if (t + 2 < 32) stageB((t + 2) % 3, t + 2);
        if (t + 1 < 32) loadA(aNext, t + 1);
        // single wait point: aCur + B(t+1) retired; 6 newest stay in flight
        if (t < 30)       asm volatile("s_waitcnt vmcnt(6) lgkmcnt(0)" ::: "memory");
        else if (t == 30) asm volatile("s_waitcnt vmcnt(4) lgkmcnt(0)" ::: "memory");
        else              asm volatile("s_waitcnt vmcnt(0) lgkmcnt(0)" ::: "memory");
        __builtin_amdgcn_sched_barrier(0);
#pragma unroll
        for (int kk = 0; kk < 2; ++kk)
#pragma unroll
            for (int m = 0; m < 2; ++m)
#pragma unroll
                for (int n = 0; n < 4; ++n)
                    iacc[m][n] = __builtin_amdgcn_mfma_i32_16x16x64_i8(aCur[m][kk], bf[n][kk], iacc[m][n], 0, 0, 0);
        if (t == 28) flush(0);          // seg0: K [0,3712)
        else if (t == 30) flush(1);     // seg1: K [3712,3968)
    };

    v4i aA[2][2], aB[2][2];
    stageB(0, 0);
    stageB(1, 1);
    loadA(aA, 0);
    asm volatile("s_waitcnt vmcnt(6)" ::: "memory");   // B(0) landed

    for (int tt = 0; tt < 32; tt += 2) {
        body(tt,     aA, aB);
        body(tt + 1, aB, aA);
    }
    flush(2);                           // seg2: K [3968,4096)

#pragma unroll
    for (int m = 0; m < 2; ++m)
#pragma unroll
        for (int n = 0; n < 4; ++n) {
            const int colg = col0 + n * 16 + (lane & 15);
            const float bv = bias[colg];
#pragma unroll
            for (int rr = 0; rr < 4; ++rr) {
                const int rowg = row0 + w * 32 + m * 16 + ((lane >> 4) << 2) + rr;
                out[(size_t)rowg * OF + colg] = facc[m][n][rr] + bv;
            }
        }
}

// ---------------------------------------------------------------------------
// workspace layout (bytes):
//   qX     @ 0          :  1,048,576
//   qW     @ 1,048,576  : 45,088,768
//   sX     @ 46,137,344 :      3,072
//   sW     @ 46,140,416 :    132,096
//   src_of @ 46,272,512 :     16,384
//   seg8   @ 46,288,896 :      4,096
// ---------------------------------------------------------------------------
extern "C" void kernel_launch(void* const* d_in, const int* in_sizes, int n_in,
                              void* d_out, int out_size, void* d_ws, size_t ws_size,
                              hipStream_t stream) {
    const float* x    = (const float*)d_in[0];
    const float* W    = (const float*)d_in[1];
    const float* bias = (const float*)d_in[2];
    const int*   ridx = (const int*)d_in[3];
    float* out = (float*)d_out;

    uint8_t* ws = (uint8_t*)d_ws;
    int8_t* qX = (int8_t*)ws;
    int8_t* qW = (int8_t*)(ws + 1048576);
    float*  sX = (float*)(ws + 46137344);
    float*  sW = (float*)(ws + 46140416);
    int* src_of = (int*)(ws + 46272512);
    uint8_t* seg8 = ws + 46288896;

    perm_k<<<1, 256, 0, stream>>>(ridx, src_of, seg8);
    quant_k<<<T_ROWS + OF, 256, 0, stream>>>(x, W, src_of, seg8, qX, qW, sX, sW);
    gemm_k<<<344, 256, 0, stream>>>(qX, qW, sX, sW, bias, out);
}